// Round 11
// baseline (203.283 us; speedup 1.0000x reference)
//
#include <hip/hip_runtime.h>
#include <hip/hip_fp16.h>

#define H_ 128
#define W_ 128
#define HW_ (H_ * W_)
#define B_ 4
#define CH2_ (2 * HW_)   // 32768 floats
#define NT_ 1024

// Scatter one event into the single-channel LDS histogram (masked by polarity pass).
__device__ __forceinline__ void scatter_one(float4 ev, int pass,
                                            float* __restrict__ hist,
                                            const __half2* __restrict__ flds) {
    bool mine = (ev.w > 0.5f) == (pass == 0);   // pass 0 = positive channel
    int py = __float2int_rn(ev.y);
    int px = __float2int_rn(ev.z);
    int pidx = max(0, min(HW_ - 1, py * W_ + px));
    __half2 f2 = flds[pidx];                    // LDS gather: (fx, fy)
    float fx = __low2float(f2);
    float fy = __high2float(f2);

    float rts = 1.0f - ev.x;                    // (1 - ts)
    float wy = fmaf(rts, fy, ev.y);             // warped y (flow ch1)
    float wx = fmaf(rts, fx, ev.z);             // warped x (flow ch0)

    float tyf = floorf(wy), lxf = floorf(wx);
    float fyf = wy - tyf;                       // bottom-row weight
    float fxf = wx - lxf;                       // right-col weight
    int ity = (int)tyf, ilx = (int)lxf;

    float wr0 = 1.0f - fyf, wr1 = fyf;
    float wc0 = 1.0f - fxf, wc1 = fxf;

    bool y0 = mine & (ity >= 0) & (ity < H_);
    bool y1 = mine & (ity + 1 >= 0) & (ity + 1 < H_);
    bool x0 = (ilx >= 0) & (ilx < W_);
    bool x1 = (ilx + 1 >= 0) & (ilx + 1 < W_);

    if (y0 & x0) atomicAdd(hist + ity * W_ + ilx,           wr0 * wc0);
    if (y0 & x1) atomicAdd(hist + ity * W_ + ilx + 1,       wr0 * wc1);
    if (y1 & x0) atomicAdd(hist + (ity + 1) * W_ + ilx,     wr1 * wc0);
    if (y1 & x1) atomicAdd(hist + (ity + 1) * W_ + ilx + 1, wr1 * wc1);
}

// Kernel 1: LDS-staged flow (half2, 64 KB) + single-channel LDS histogram
// (64 KB), two polarity passes over the block's event chunk. No divergent
// global gathers, no global atomics.
__global__ __launch_bounds__(NT_, 4)
void event_hist_kernel(const float* __restrict__ event_list,
                       const float* __restrict__ flow,
                       float* __restrict__ ws,
                       int nN, int bpb, int cs) {
    __shared__ float   hist[HW_];    // 64 KB
    __shared__ __half2 flds[HW_];    // 64 KB
    int tid = threadIdx.x;
    int b = blockIdx.x / bpb;
    int j = blockIdx.x - b * bpb;

    // stage flow for batch b: (fx = ch0, fy = ch1) per pixel
    const float* fb = flow + (size_t)b * CH2_;
    for (int i = tid; i < HW_; i += NT_)
        flds[i] = __floats2half2_rn(fb[i], fb[HW_ + i]);

    const float4* evb = reinterpret_cast<const float4*>(event_list) + (size_t)b * nN;
    int start = j * cs;
    int end = min(nN, start + cs);

    for (int pass = 0; pass < 2; ++pass) {
        for (int i = tid; i < HW_; i += NT_) hist[i] = 0.0f;
        __syncthreads();

        int i = start + tid;
        // 4 events per iteration: phase the 4 independent stream loads first
        for (; i + 3 * NT_ < end; i += 4 * NT_) {
            float4 ev[4];
            #pragma unroll
            for (int u = 0; u < 4; ++u) ev[u] = evb[i + u * NT_];
            #pragma unroll
            for (int u = 0; u < 4; ++u) scatter_one(ev[u], pass, hist, flds);
        }
        for (; i < end; i += NT_) scatter_one(evb[i], pass, hist, flds);

        __syncthreads();
        // dump this channel's partial: ws[b][j][pass][HW], coalesced float4
        float* wsb = ws + ((size_t)(b * bpb + j) * 2 + pass) * HW_;
        for (int i2 = tid; i2 < HW_ / 4; i2 += NT_)
            reinterpret_cast<float4*>(wsb)[i2] =
                reinterpret_cast<const float4*>(hist)[i2];
        __syncthreads();   // hist re-zeroed next pass
    }
}

// Kernel 2: reduce bpb partials per (b, ch, pix) + fused avg_flow pass.
__global__ void reduce_kernel(const float* __restrict__ ws,
                              const float* __restrict__ flow,
                              const float* __restrict__ event_mask,
                              float* __restrict__ out, int bpb) {
    int idx = blockIdx.x * blockDim.x + threadIdx.x;
    if (idx >= B_ * CH2_) return;
    int b = idx / CH2_;
    int r = idx - b * CH2_;            // r = ch*HW + pix

    const float* base = ws + (size_t)b * bpb * CH2_ + r;
    float s = 0.0f;
    #pragma unroll 8
    for (int j = 0; j < bpb; ++j) s += base[(size_t)j * CH2_];

    int ch  = r / HW_;
    int pix = r - ch * HW_;
    float* ob = out + (size_t)b * 4 * HW_;
    ob[ch * HW_ + pix] = s;                          // iwe channel

    float m = event_mask[b * HW_ + pix];
    float f = flow[(size_t)b * CH2_ + r];
    ob[(2 + ch) * HW_ + pix] = f * m / (m + 1e-9f);  // avg_flow channel
}

extern "C" void kernel_launch(void* const* d_in, const int* in_sizes, int n_in,
                              void* d_out, int out_size, void* d_ws, size_t ws_size,
                              hipStream_t stream) {
    const float* flow       = (const float*)d_in[0];  // [B,2,H,W]
    const float* event_list = (const float*)d_in[1];  // [B,N,4]
    const float* event_mask = (const float*)d_in[3];  // [B,1,H,W]
    float* out = (float*)d_out;                       // [B,4,H,W]
    float* ws  = (float*)d_ws;

    int nN = in_sizes[1] / (B_ * 4);                  // events per batch

    // partials need B*bpb*CH2_*4 bytes; shrink bpb if workspace is small
    int bpb = 64;
    while (bpb > 1 && (size_t)B_ * bpb * CH2_ * 4 > ws_size) bpb >>= 1;
    int cs = (nN + bpb - 1) / bpb;                    // events per block

    event_hist_kernel<<<B_ * bpb, NT_, 0, stream>>>(event_list, flow, ws, nN, bpb, cs);

    int n2 = B_ * CH2_;
    reduce_kernel<<<(n2 + 255) / 256, 256, 0, stream>>>(ws, flow, event_mask, out, bpb);
}

// Round 18
// 193.634 us; speedup vs baseline: 1.0498x; 1.0498x over previous
//
#include <hip/hip_runtime.h>

#define H_ 128
#define W_ 128
#define HW_ (H_ * W_)
#define B_ 4
#define CH2_ (2 * HW_)   // 32768 floats
#define NT_ 1024

// Scatter one event into the single-channel LDS histogram if it matches this
// block's polarity. Flow gathered directly from global (L2/L3-resident).
__device__ __forceinline__ void scatter_one(float4 ev, int pol,
                                            float* __restrict__ hist,
                                            const float* __restrict__ fb) {
    bool mine = ((ev.w > 0.5f) ? 0 : 1) == pol;   // pol 0 = positive channel
    if (!mine) return;                             // exec-masked, no syncs inside

    int py = __float2int_rn(ev.y);
    int px = __float2int_rn(ev.z);
    int pidx = max(0, min(HW_ - 1, py * W_ + px));
    float fx = fb[pidx];            // flow channel 0 (x)
    float fy = fb[HW_ + pidx];      // flow channel 1 (y)

    float rts = 1.0f - ev.x;        // (1 - ts)
    float wy = fmaf(rts, fy, ev.y); // warped y (flow ch1)
    float wx = fmaf(rts, fx, ev.z); // warped x (flow ch0)

    float tyf = floorf(wy), lxf = floorf(wx);
    float fyf = wy - tyf;           // bottom-row weight
    float fxf = wx - lxf;           // right-col weight
    int ity = (int)tyf, ilx = (int)lxf;

    float wr0 = 1.0f - fyf, wr1 = fyf;
    float wc0 = 1.0f - fxf, wc1 = fxf;

    bool y0 = (ity >= 0) & (ity < H_);
    bool y1 = (ity + 1 >= 0) & (ity + 1 < H_);
    bool x0 = (ilx >= 0) & (ilx < W_);
    bool x1 = (ilx + 1 >= 0) & (ilx + 1 < W_);

    if (y0 & x0) atomicAdd(hist + ity * W_ + ilx,           wr0 * wc0);
    if (y0 & x1) atomicAdd(hist + ity * W_ + ilx + 1,       wr0 * wc1);
    if (y1 & x0) atomicAdd(hist + (ity + 1) * W_ + ilx,     wr1 * wc0);
    if (y1 & x1) atomicAdd(hist + (ity + 1) * W_ + ilx + 1, wr1 * wc1);
}

// Kernel 1: one polarity channel per block, 64 KB LDS histogram ->
// 2 blocks/CU co-resident = 32 waves/CU (vs 16 before). Grid = B*bpb*2.
__global__ __launch_bounds__(NT_, 8)
void event_hist_kernel(const float* __restrict__ event_list,
                       const float* __restrict__ flow,
                       float* __restrict__ ws,
                       int nN, int bpb, int cs) {
    __shared__ float hist[HW_];      // 64 KB
    int tid = threadIdx.x;
    int b   = blockIdx.x / (bpb * 2);
    int rem = blockIdx.x - b * (bpb * 2);
    int j   = rem >> 1;
    int pol = rem & 1;

    for (int i = tid; i < HW_; i += NT_) hist[i] = 0.0f;
    __syncthreads();

    const float* fb = flow + (size_t)b * CH2_;
    const float4* evb = reinterpret_cast<const float4*>(event_list) + (size_t)b * nN;
    int start = j * cs;
    int end = min(nN, start + cs);

    int i = start + tid;
    // 4 events per iteration: phase the 4 independent stream loads first
    for (; i + 3 * NT_ < end; i += 4 * NT_) {
        float4 ev[4];
        #pragma unroll
        for (int u = 0; u < 4; ++u) ev[u] = evb[i + u * NT_];
        #pragma unroll
        for (int u = 0; u < 4; ++u) scatter_one(ev[u], pol, hist, fb);
    }
    for (; i < end; i += NT_) scatter_one(evb[i], pol, hist, fb);

    __syncthreads();
    // dump this channel's partial: ws[b][j][pol][HW], coalesced float4
    float* wsb = ws + ((size_t)(b * bpb + j) * 2 + pol) * HW_;
    for (int i2 = tid; i2 < HW_ / 4; i2 += NT_)
        reinterpret_cast<float4*>(wsb)[i2] =
            reinterpret_cast<const float4*>(hist)[i2];
}

// Kernel 2: reduce bpb partials per (b, ch, pix) + fused avg_flow pass.
__global__ void reduce_kernel(const float* __restrict__ ws,
                              const float* __restrict__ flow,
                              const float* __restrict__ event_mask,
                              float* __restrict__ out, int bpb) {
    int idx = blockIdx.x * blockDim.x + threadIdx.x;
    if (idx >= B_ * CH2_) return;
    int b = idx / CH2_;
    int r = idx - b * CH2_;            // r = ch*HW + pix

    const float* base = ws + (size_t)b * bpb * CH2_ + r;
    float s = 0.0f;
    #pragma unroll 8
    for (int j = 0; j < bpb; ++j) s += base[(size_t)j * CH2_];

    int ch  = r / HW_;
    int pix = r - ch * HW_;
    float* ob = out + (size_t)b * 4 * HW_;
    ob[ch * HW_ + pix] = s;                          // iwe channel

    float m = event_mask[b * HW_ + pix];
    float f = flow[(size_t)b * CH2_ + r];
    ob[(2 + ch) * HW_ + pix] = f * m / (m + 1e-9f);  // avg_flow channel
}

extern "C" void kernel_launch(void* const* d_in, const int* in_sizes, int n_in,
                              void* d_out, int out_size, void* d_ws, size_t ws_size,
                              hipStream_t stream) {
    const float* flow       = (const float*)d_in[0];  // [B,2,H,W]
    const float* event_list = (const float*)d_in[1];  // [B,N,4]
    const float* event_mask = (const float*)d_in[3];  // [B,1,H,W]
    float* out = (float*)d_out;                       // [B,4,H,W]
    float* ws  = (float*)d_ws;

    int nN = in_sizes[1] / (B_ * 4);                  // events per batch

    // partials need B*bpb*CH2_*4 bytes; shrink bpb if workspace is small
    int bpb = 64;
    while (bpb > 1 && (size_t)B_ * bpb * CH2_ * 4 > ws_size) bpb >>= 1;
    int cs = (nN + bpb - 1) / bpb;                    // events per block

    event_hist_kernel<<<B_ * bpb * 2, NT_, 0, stream>>>(event_list, flow, ws, nN, bpb, cs);

    int n2 = B_ * CH2_;
    reduce_kernel<<<(n2 + 255) / 256, 256, 0, stream>>>(ws, flow, event_mask, out, bpb);
}